// Round 1
// 448.879 us; speedup vs baseline: 1.0638x; 1.0638x over previous
//
#include <hip/hip_runtime.h>
#include <cstdint>

#define EPS 1e-5f
constexpr int B = 4, C = 512, HW = 16384, K = 32;

typedef __bf16 bf16x8 __attribute__((ext_vector_type(8)));
typedef float  floatx4 __attribute__((ext_vector_type(4)));
typedef unsigned int u32;

__device__ __forceinline__ void load_lds16(const void* g, void* l) {
    __builtin_amdgcn_global_load_lds((const __attribute__((address_space(1))) u32*)g,
                                     (__attribute__((address_space(3))) u32*)l,
                                     16, 0, 0);
}

// ---------------------------------------------------------------------------
// workspace byte offsets
constexpr size_t Z_OFF     = 0;            // z bf16 [b][n][c]    67,108,864
constexpr size_t WBB_OFF   = 67108864;     // W bf16 frag-swizzled   524,288
constexpr size_t CWB_OFF   = 67633152;     // cw bf16 [k][c]          32,768
constexpr size_t X2_OFF    = 67665920;     // fp32 [b*HW]            262,144
constexpr size_t C2_OFF    = 67928064;     // fp32 [K]
constexpr size_t ASUM_OFF  = 67928192;     // fp32 [B*K]
constexpr size_t PART_OFF  = 67928704;     // fp32 [B][128][K][C] 33,554,432
constexpr size_t AGG_OFF   = 101483136;    // fp32 [B][K][C]         262,144
constexpr size_t GAMMA_OFF = 101745280;    // fp32 [B][C]

// ---------------------------------------------------------------------------
// prep:
//  blocks 0..127  : conv_w fp32 -> wbb bf16 in MFMA-fragment order:
//                   wbb[(((t*8 + i)*2 + ks)*64 + lane)*8 + j] =
//                     W[t*16 + (lane&15)][i*64 + ks*32 + (lane>>4)*8 + j]
//                   (t = o>>4 tile 0..31, i = 64-c chunk 0..7, ks = 32-c half)
//                   -> each (t,i,ks) fragment is 1KB contiguous per wave read.
//  blocks 128..131: cw fp32 -> cwb bf16 [k][c]
//  block  132     : c2[k] = ||cw_k||^2 ; zero asum
__global__ __launch_bounds__(256) void prep_kernel(
    const float* __restrict__ conv_w, const float* __restrict__ cw,
    __bf16* __restrict__ wbb, __bf16* __restrict__ cwb,
    float* __restrict__ c2, float* __restrict__ asum) {
    const int tid = threadIdx.x, bx = blockIdx.x;
    if (bx < 128) {
        const int idx  = bx * 256 + tid;          // [0, 32768)
        const int lane = idx & 63;
        const int ks   = (idx >> 6) & 1;
        const int ii   = (idx >> 7) & 7;
        const int t    = idx >> 10;
        const float* s = conv_w + (size_t)(t * 16 + (lane & 15)) * C
                         + ii * 64 + ks * 32 + (lane >> 4) * 8;
        bf16x8 o;
        #pragma unroll
        for (int j = 0; j < 8; j++) o[j] = (__bf16)s[j];
        *(bf16x8*)&wbb[(size_t)idx * 8] = o;
    } else if (bx < 132) {
        const int idx = ((bx - 128) * 256 + tid) * 16;   // [0, 16384) elems
        const float* s = cw + idx;
        __bf16* d = cwb + idx;
        bf16x8 o0, o1;
        #pragma unroll
        for (int j = 0; j < 8; j++) o0[j] = (__bf16)s[j];
        #pragma unroll
        for (int j = 0; j < 8; j++) o1[j] = (__bf16)s[8 + j];
        *(bf16x8*)&d[0] = o0;
        *(bf16x8*)&d[8] = o1;
    } else {
        if (tid < 32) {
            const float* r = cw + tid * 512;
            float s = 0.f;
            for (int c = 0; c < 512; c++) s += r[c] * r[c];
            c2[tid] = s;
        }
        if (tid < 128) asum[tid] = 0.f;
    }
}

// ---------------------------------------------------------------------------
// fused: transpose x (in LDS) + conv GEMM (bf16 MFMA) + BN2 + ReLU + x2.
// block: 64 n x full 512 o; 4 waves each 64n x 128o (acc 128 regs/lane).
//
// v2 pipeline (per 64-c chunk):
//   __syncthreads()            <- drains vmcnt(0): chunk i landed in XR[cur];
//                                 also guarantees XA free (MFMA i-1 done)
//   stage(i+1)  -> XR[cur^1]   <- prefetch; stays in flight across the RAW
//                                 barrier below and the whole MFMA phase
//   transpose XR[cur] -> XA    <- ds only
//   s_waitcnt lgkmcnt(0); raw s_barrier   <- does NOT drain vmcnt
//   MFMA over XA (W fragments read as contiguous 1KB wave loads)
__global__ __launch_bounds__(256) void conv_fused_kernel(
    const float* __restrict__ x, const __bf16* __restrict__ wbb,
    const float* __restrict__ g2, const float* __restrict__ b2,
    const float* __restrict__ m2, const float* __restrict__ v2,
    __bf16* __restrict__ z, float* __restrict__ x2g) {
    __shared__ float  XR[2][64 * 64];   // [chunk c][n] fp32, 2x16 KB
    __shared__ __bf16 XA[64 * 72];      // [n][c-in-chunk], 9 KB (single buf)
    __shared__ float  x2L[64];
    const int tid = threadIdx.x, lane = tid & 63, w = tid >> 6;
    const int l15 = lane & 15, q = lane >> 4;
    const int n0 = blockIdx.x * 64, b = blockIdx.y;
    if (tid < 64) x2L[tid] = 0.f;

    auto stage = [&](int chunk, int buf) {
        #pragma unroll
        for (int p = 0; p < 4; p++) {
            int seg = w * 4 + p;                    // 16 segs of 4 c-rows
            int cr = chunk * 64 + seg * 4 + (lane >> 4);
            const float* gp = x + ((size_t)(b * C + cr)) * HW + n0 + (lane & 15) * 4;
            load_lds16(gp, (char*)XR[buf] + seg * 1024);
        }
    };

    floatx4 acc[4][8];
    const floatx4 zv4 = {0.f, 0.f, 0.f, 0.f};
    #pragma unroll
    for (int mt = 0; mt < 4; mt++)
        #pragma unroll
        for (int ot = 0; ot < 8; ot++) acc[mt][ot] = zv4;

    stage(0, 0);
    for (int i = 0; i < 8; i++) {
        const int cur = i & 1;
        __syncthreads();                    // chunk i landed; XA free
        if (i < 7) stage(i + 1, cur ^ 1);   // prefetch next chunk (survives below)
        // transpose+convert XR[cur] -> XA
        #pragma unroll
        for (int f = 0; f < 2; f++) {
            int id = f * 256 + tid;
            int n = id & 63, cs = id >> 6;
            bf16x8 o;
            #pragma unroll
            for (int j = 0; j < 8; j++) o[j] = (__bf16)XR[cur][(cs * 8 + j) * 64 + n];
            *(bf16x8*)&XA[n * 72 + cs * 8] = o;
        }
        asm volatile("s_waitcnt lgkmcnt(0)" ::: "memory");
        __builtin_amdgcn_sched_barrier(0);
        __builtin_amdgcn_s_barrier();       // XA ready; prefetch NOT drained
        __builtin_amdgcn_sched_barrier(0);
        #pragma unroll
        for (int ks = 0; ks < 2; ks++) {
            bf16x8 af[4], bfv[8];
            #pragma unroll
            for (int ot = 0; ot < 8; ot++)
                bfv[ot] = *(const bf16x8*)&wbb[
                    ((size_t)(((w * 8 + ot) * 8 + i) * 2 + ks) * 64 + lane) * 8];
            #pragma unroll
            for (int mt = 0; mt < 4; mt++)
                af[mt] = *(const bf16x8*)&XA[(mt * 16 + l15) * 72 + ks * 32 + q * 8];
            #pragma unroll
            for (int mt = 0; mt < 4; mt++)
                #pragma unroll
                for (int ot = 0; ot < 8; ot++)
                    acc[mt][ot] = __builtin_amdgcn_mfma_f32_16x16x32_bf16(
                        af[mt], bfv[ot], acc[mt][ot], 0, 0, 0);
        }
    }
    // epilogue: BN + ReLU + store z bf16 + x2 partials
    float s8[8], bi8[8];
    #pragma unroll
    for (int ot = 0; ot < 8; ot++) {
        int o = w * 128 + ot * 16 + l15;
        float s = g2[o] * rsqrtf(v2[o] + EPS);
        s8[ot] = s; bi8[ot] = b2[o] - m2[o] * s;
    }
    float xx[16];
    #pragma unroll
    for (int t = 0; t < 16; t++) xx[t] = 0.f;
    #pragma unroll
    for (int mt = 0; mt < 4; mt++)
        #pragma unroll
        for (int reg = 0; reg < 4; reg++) {
            int n = n0 + mt * 16 + q * 4 + reg;
            #pragma unroll
            for (int ot = 0; ot < 8; ot++) {
                float v = fmaxf(acc[mt][ot][reg] * s8[ot] + bi8[ot], 0.f);
                z[((size_t)(b * HW + n)) * C + w * 128 + ot * 16 + l15] = (__bf16)v;
                xx[mt * 4 + reg] += v * v;
            }
        }
    #pragma unroll
    for (int t = 0; t < 16; t++) {
        float v = xx[t];
        v += __shfl_xor(v, 1); v += __shfl_xor(v, 2);
        v += __shfl_xor(v, 4); v += __shfl_xor(v, 8);
        xx[t] = v;
    }
    if (l15 == 0) {
        #pragma unroll
        for (int mt = 0; mt < 4; mt++)
            #pragma unroll
            for (int reg = 0; reg < 4; reg++)
                atomicAdd(&x2L[mt * 16 + q * 4 + reg], xx[mt * 4 + reg]);
    }
    __syncthreads();
    if (tid < 64) x2g[(size_t)b * HW + n0 + tid] = x2L[tid];
}

// ---------------------------------------------------------------------------
// fused assign+agg: per block 128 n (4 sub-tiles of 32).
// per sub-tile: stage z[32][512] in LDS (pad to 528) -> assign MFMA (cw from
// global/L1) -> in-LDS logit exchange -> softmax -> AT [k][n] bf16 in LDS ->
// agg MFMA (A=AT contiguous, B=z^T strided u16). agg acc persists in VGPRs.
__global__ __launch_bounds__(256) void assign_agg_kernel(
    const __bf16* __restrict__ zb, const __bf16* __restrict__ cwb,
    const float* __restrict__ scale, const float* __restrict__ c2,
    const float* __restrict__ x2g, float* __restrict__ part,
    float* __restrict__ asum) {
    __shared__ __bf16 ZT[32][528];   // 33 KB
    __shared__ float  LG[32][33];    // logits [k][n]
    __shared__ __bf16 AT[32][40];    // assign [k][n]
    __shared__ float  asum_l[32];
    const int tid = threadIdx.x, lane = tid & 63, w = tid >> 6;
    const int l15 = lane & 15, q = lane >> 4;
    const int b = blockIdx.y, bx = blockIdx.x;
    if (tid < 32) asum_l[tid] = 0.f;
    float sck[8], c2k[8];
    #pragma unroll
    for (int j = 0; j < 8; j++) { sck[j] = scale[q * 8 + j]; c2k[j] = c2[q * 8 + j]; }
    const int mt_ = w >> 1, nt_ = w & 1;

    floatx4 agga[2][8];
    const floatx4 zv4 = {0.f, 0.f, 0.f, 0.f};
    #pragma unroll
    for (int mt = 0; mt < 2; mt++)
        #pragma unroll
        for (int ct = 0; ct < 8; ct++) agga[mt][ct] = zv4;

    for (int s = 0; s < 4; s++) {
        const int nb = bx * 128 + s * 32;
        bf16x8 st[8];
        #pragma unroll
        for (int p = 0; p < 8; p++) {
            int e = (p * 256 + tid) * 8;
            int n = e >> 9, c = e & 511;
            st[p] = *(const bf16x8*)&zb[((size_t)(b * HW + nb + n)) * C + c];
        }
        __syncthreads();   // prev sub-tile compute done reading ZT
        #pragma unroll
        for (int p = 0; p < 8; p++) {
            int e = (p * 256 + tid) * 8;
            int n = e >> 9, c = e & 511;
            *(bf16x8*)&ZT[n][c] = st[p];
        }
        __syncthreads();
        // ---- assign MFMA: each wave one (mt_, nt_) 16x16 tile, full K=512
        floatx4 la = zv4;
        #pragma unroll
        for (int kc = 0; kc < 16; kc++) {
            bf16x8 a  = *(const bf16x8*)&cwb[(size_t)(mt_ * 16 + l15) * C + kc * 32 + q * 8];
            bf16x8 bb = *(const bf16x8*)&ZT[nt_ * 16 + l15][kc * 32 + q * 8];
            la = __builtin_amdgcn_mfma_f32_16x16x32_bf16(a, bb, la, 0, 0, 0);
        }
        #pragma unroll
        for (int r = 0; r < 4; r++)
            LG[mt_ * 16 + q * 4 + r][nt_ * 16 + l15] = la[r];
        __syncthreads();
        // ---- softmax over k (waves 0,1 cover the 32 n-columns)
        if (w < 2) {
            int nl = w * 16 + l15;
            float x2v = x2g[(size_t)b * HW + nb + nl];
            float lg[8];
            float mx = -1e30f;
            #pragma unroll
            for (int j = 0; j < 8; j++) {
                float t = sck[j] * (x2v - 2.f * LG[q * 8 + j][nl] + c2k[j]);
                lg[j] = t; mx = fmaxf(mx, t);
            }
            mx = fmaxf(mx, __shfl_xor(mx, 16));
            mx = fmaxf(mx, __shfl_xor(mx, 32));
            float se = 0.f;
            #pragma unroll
            for (int j = 0; j < 8; j++) { lg[j] = __expf(lg[j] - mx); se += lg[j]; }
            se += __shfl_xor(se, 16);
            se += __shfl_xor(se, 32);
            float inv = 1.f / se;
            #pragma unroll
            for (int j = 0; j < 8; j++) {
                float a = lg[j] * inv;
                AT[q * 8 + j][nl] = (__bf16)a;
                lg[j] = a;
            }
            #pragma unroll
            for (int j = 0; j < 8; j++) {
                float v = lg[j];
                v += __shfl_xor(v, 1); v += __shfl_xor(v, 2);
                v += __shfl_xor(v, 4); v += __shfl_xor(v, 8);
                if (l15 == 0) atomicAdd(&asum_l[q * 8 + j], v);
            }
        }
        __syncthreads();
        // ---- agg MFMA: Kdim = 32 n (one chunk); per wave 8 c-tiles
        bf16x8 afr0 = *(const bf16x8*)&AT[l15][q * 8];
        bf16x8 afr1 = *(const bf16x8*)&AT[16 + l15][q * 8];
        #pragma unroll
        for (int ct = 0; ct < 8; ct++) {
            int c = w * 128 + ct * 16 + l15;
            bf16x8 bb;
            #pragma unroll
            for (int j = 0; j < 8; j++) bb[j] = ZT[q * 8 + j][c];
            agga[0][ct] = __builtin_amdgcn_mfma_f32_16x16x32_bf16(afr0, bb, agga[0][ct], 0, 0, 0);
            agga[1][ct] = __builtin_amdgcn_mfma_f32_16x16x32_bf16(afr1, bb, agga[1][ct], 0, 0, 0);
        }
    }
    // epilogue: per-block agg partials
    float* pp = part + ((size_t)(b * 128 + bx) * K) * C;
    #pragma unroll
    for (int mt = 0; mt < 2; mt++)
        #pragma unroll
        for (int ct = 0; ct < 8; ct++)
            #pragma unroll
            for (int r = 0; r < 4; r++)
                pp[(size_t)(mt * 16 + q * 4 + r) * C + w * 128 + ct * 16 + l15] =
                    agga[mt][ct][r];
    __syncthreads();
    if (tid < 32) atomicAdd(&asum[b * K + tid], asum_l[tid]);
}

// ---------------------------------------------------------------------------
__global__ __launch_bounds__(512) void agg_reduce_kernel(
    const float* __restrict__ part, float* __restrict__ agg) {
    const int k = blockIdx.x, b = blockIdx.y, c = threadIdx.x;
    float s = 0.f;
    for (int p = 0; p < 128; p++)
        s += part[((size_t)((b * 128 + p) * K + k)) * C + c];
    agg[((size_t)(b * K + k)) * C + c] = s;
}

// ---------------------------------------------------------------------------
// feat = mean_k relu(bn1(agg - asum*cw)); gamma = sigmoid(fc_w @ feat + fc_b)
__global__ __launch_bounds__(512) void feat_kernel(
    const float* __restrict__ cw,
    const float* __restrict__ g1, const float* __restrict__ b1,
    const float* __restrict__ m1, const float* __restrict__ v1,
    const float* __restrict__ fcw, const float* __restrict__ fcb,
    const float* __restrict__ agg, const float* __restrict__ asum,
    float* __restrict__ gamma, float* __restrict__ out_feat) {
    __shared__ float featL[C];
    const int tid = threadIdx.x;
    const int b = blockIdx.x;
    float f = 0.f;
    for (int kk = 0; kk < K; kk++) {
        float s = g1[kk] * rsqrtf(v1[kk] + EPS);
        float bias = b1[kk] - m1[kk] * s;
        float e = agg[((size_t)b * K + kk) * C + tid] - asum[b * K + kk] * cw[kk * C + tid];
        f += fmaxf(e * s + bias, 0.f);
    }
    f *= (1.f / 32.f);
    out_feat[b * C + tid] = f;
    featL[tid] = f;
    __syncthreads();
    const int w = tid >> 6, l = tid & 63;
    for (int cc = w * 64; cc < w * 64 + 64; cc++) {
        const float* row = &fcw[(size_t)cc * C + l * 8];
        float4 fa = *(const float4*)&featL[l * 8];
        float4 fb = *(const float4*)&featL[l * 8 + 4];
        float4 wa = *(const float4*)row;
        float4 wb = *(const float4*)(row + 4);
        float s = fa.x * wa.x + fa.y * wa.y + fa.z * wa.z + fa.w * wa.w
                + fb.x * wb.x + fb.y * wb.y + fb.z * wb.z + fb.w * wb.w;
        #pragma unroll
        for (int d = 32; d >= 1; d >>= 1) s += __shfl_xor(s, d);
        if (l == 0) gamma[b * C + cc] = 1.f / (1.f + __expf(-(s + fcb[cc])));
    }
}

// ---------------------------------------------------------------------------
// out = relu(x * (1 + gamma[b,c]))
__global__ __launch_bounds__(256) void gate_kernel(const float* __restrict__ x,
                                                   const float* __restrict__ gamma,
                                                   float* __restrict__ out) {
    size_t idx = (size_t)blockIdx.x * 256 + threadIdx.x;
    int bc = (int)(idx >> 12);
    float gm = 1.f + gamma[bc];
    float4 xv = ((const float4*)x)[idx];
    float4 r;
    r.x = fmaxf(xv.x * gm, 0.f);
    r.y = fmaxf(xv.y * gm, 0.f);
    r.z = fmaxf(xv.z * gm, 0.f);
    r.w = fmaxf(xv.w * gm, 0.f);
    ((float4*)out)[idx] = r;
}

// ---------------------------------------------------------------------------
extern "C" void kernel_launch(void* const* d_in, const int* in_sizes, int n_in,
                              void* d_out, int out_size, void* d_ws, size_t ws_size,
                              hipStream_t stream) {
    const float* x      = (const float*)d_in[0];
    const float* conv_w = (const float*)d_in[1];
    const float* bn2_g  = (const float*)d_in[2];
    const float* bn2_b  = (const float*)d_in[3];
    const float* bn2_m  = (const float*)d_in[4];
    const float* bn2_v  = (const float*)d_in[5];
    const float* cw     = (const float*)d_in[6];
    const float* scale  = (const float*)d_in[7];
    const float* bn1_g  = (const float*)d_in[8];
    const float* bn1_b  = (const float*)d_in[9];
    const float* bn1_m  = (const float*)d_in[10];
    const float* bn1_v  = (const float*)d_in[11];
    const float* fcw    = (const float*)d_in[12];
    const float* fcb    = (const float*)d_in[13];
    char* wsb = (char*)d_ws;
    __bf16* zbuf  = (__bf16*)(wsb + Z_OFF);
    __bf16* wbb   = (__bf16*)(wsb + WBB_OFF);
    __bf16* cwb   = (__bf16*)(wsb + CWB_OFF);
    float*  x2    = (float*)(wsb + X2_OFF);
    float*  c2    = (float*)(wsb + C2_OFF);
    float*  asum  = (float*)(wsb + ASUM_OFF);
    float*  part  = (float*)(wsb + PART_OFF);
    float*  agg   = (float*)(wsb + AGG_OFF);
    float*  gamma = (float*)(wsb + GAMMA_OFF);
    float* out = (float*)d_out;

    prep_kernel<<<133, 256, 0, stream>>>(conv_w, cw, wbb, cwb, c2, asum);
    conv_fused_kernel<<<dim3(256, 4), 256, 0, stream>>>(
        x, wbb, bn2_g, bn2_b, bn2_m, bn2_v, zbuf, x2);
    assign_agg_kernel<<<dim3(128, 4), 256, 0, stream>>>(
        zbuf, cwb, scale, c2, x2, part, asum);
    agg_reduce_kernel<<<dim3(32, 4), 512, 0, stream>>>(part, agg);
    feat_kernel<<<4, 512, 0, stream>>>(cw, bn1_g, bn1_b, bn1_m, bn1_v,
                                       fcw, fcb, agg, asum, gamma, out);
    gate_kernel<<<32768, 256, 0, stream>>>(x, gamma, out + B * C);
}